// Round 14
// baseline (261.003 us; speedup 1.0000x reference)
//
#include <hip/hip_runtime.h>
#include <math.h>

typedef unsigned short ushort_t;
typedef __attribute__((ext_vector_type(8))) short bf16x8;   // MFMA A/B frag (4 VGPR)
typedef __attribute__((ext_vector_type(4))) float f32x4;    // MFMA C/D frag

// ---------------------------------------------------------------------------
// DPP-based add: x += x[lane ^ pattern], pure VALU.
// ---------------------------------------------------------------------------
template<int CTRL>
__device__ __forceinline__ float dpp_addf(float x)
{
    int y = __builtin_amdgcn_update_dpp(0, __float_as_int(x), CTRL, 0xf, 0xf, true);
    return x + __int_as_float(y);
}

template<int LPE>
__device__ __forceinline__ float group_reduce(float p)
{
    p = dpp_addf<0xB1>(p);                           // xor 1
    p = dpp_addf<0x4E>(p);                           // xor 2
    if constexpr (LPE >= 8)  p = dpp_addf<0x141>(p); // xor 7
    if constexpr (LPE >= 16) p = dpp_addf<0x140>(p); // xor 15
    return p;
}

__device__ __forceinline__ ushort_t f2bf(float f)
{
    unsigned u = __float_as_uint(f);
    return (ushort_t)((u + 0x7fffu + ((u >> 16) & 1u)) >> 16);   // RNE
}

// ---------------------------------------------------------------------------
// setup: zero cnt + convert all four weight matrices to bf16.
// Fuses the old hipMemsetAsync + conv_w (one dispatch saved; ~8us overhead
// per dispatch measured via r4/r13 budget residuals).
// ---------------------------------------------------------------------------
__global__ __launch_bounds__(256)
void setup_kernel(const float* __restrict__ Wl1, const float* __restrict__ Wr1,
                  const float* __restrict__ Wl2, const float* __restrict__ Wr2,
                  ushort_t* __restrict__ wab1, ushort_t* __restrict__ wab2,
                  int* __restrict__ cnt, int n)
{
    const int T = gridDim.x * 256;
    const int i0 = blockIdx.x * 256 + threadIdx.x;
    for (int k = i0; k < n; k += T) cnt[k] = 0;
    for (int k = i0; k < 2 * 64 * 128; k += T)
        wab1[k] = f2bf(k < 64 * 128 ? Wl1[k] : Wr1[k - 64 * 128]);
    for (int k = i0; k < 2 * 32 * 64; k += T)
        wab2[k] = f2bf(k < 32 * 64 ? Wl2[k] : Wr2[k - 32 * 64]);
}

// ---------------------------------------------------------------------------
// deg: in-degree count + per-edge arrival rank (enables atomic-free scatter)
// ---------------------------------------------------------------------------
__global__ __launch_bounds__(256)
void deg_kernel(const int* __restrict__ ei, int* __restrict__ cnt,
                int* __restrict__ rank, int E)
{
    int e = blockIdx.x * 256 + threadIdx.x;
    if (e >= E) return;
    rank[e] = atomicAdd(&cnt[ei[E + e]], 1);
}

// ---------------------------------------------------------------------------
// scan_all: ONE dispatch replaces scan_p1+scan_p3. Each of nb (<=256) blocks
// redundantly computes ALL tile sums (thread t sums tile t — ~200KB L2-read
// per block, 39MB total, ~1-2us), scans them in LDS, then scans its own
// 256-node tile. Zero inter-block communication.
// ---------------------------------------------------------------------------
__global__ __launch_bounds__(256)
void scan_all(const int* __restrict__ cnt, int* __restrict__ row_off,
              int n, int nb)
{
    __shared__ int tsum[256];
    __shared__ int s[256];
    const int tid = threadIdx.x;

    // per-thread: sum of tile `tid`
    int sum = 0;
    if (tid < nb) {
        const int base = tid * 256;
        const int lim = min(256, n - base);
        int i = 0;
        for (; i + 4 <= lim; i += 4) {
            int4 v = *(const int4*)(cnt + base + i);
            sum += (v.x + v.y) + (v.z + v.w);
        }
        for (; i < lim; ++i) sum += cnt[base + i];
    }
    tsum[tid] = sum;
    __syncthreads();
    const int own_b = tsum[blockIdx.x];         // tile sum of this block
    #pragma unroll
    for (int off = 1; off < 256; off <<= 1) {   // inclusive scan of tile sums
        int t = (tid >= off) ? tsum[tid - off] : 0;
        __syncthreads();
        tsum[tid] += t;
        __syncthreads();
    }
    const int base = tsum[blockIdx.x] - own_b;  // exclusive prefix for tile

    int gi = blockIdx.x * 256 + tid;
    int c = (gi < n) ? cnt[gi] : 0;
    s[tid] = c;
    __syncthreads();
    #pragma unroll
    for (int off = 1; off < 256; off <<= 1) {   // inclusive scan of own tile
        int t = (tid >= off) ? s[tid - off] : 0;
        __syncthreads();
        s[tid] += t;
        __syncthreads();
    }
    if (gi < n) {
        int excl = base + s[tid] - c;
        row_off[gi] = excl;
        if (gi == n - 1) row_off[n] = excl + c; // == E
    }
}

// atomic-free scatter: slot position = row_off[dst] + rank
__global__ __launch_bounds__(256)
void scatter_kernel(const int* __restrict__ ei, const float* __restrict__ ew,
                    const int* __restrict__ row_off, const int* __restrict__ rank,
                    int2* __restrict__ slot, int E)
{
    int e = blockIdx.x * 256 + threadIdx.x;
    if (e >= E) return;
    int d = ei[E + e];
    slot[row_off[d] + rank[e]] = make_int2(ei[e], __float_as_int(ew[e]));
}

// ---------------------------------------------------------------------------
// MFMA fused linear: C[m][col] = sum_k X[m][k]*W[col][k] + bias[col], bf16 out.
// W pre-converted bf16 (rows 0..N/2-1 = Wa, N/2..N-1 = Wb) -> staging is a
// pure 16B copy. XOR-granule-swizzled LDS (granule g at phys g^(row&7)):
// conflict-free bf16x8 fragment reads. Layouts HW-verified (m89/m91):
// A/B frag [m|n=lane&15][k=quad*8+j]; C/D col=lane&15, row=quad*4+reg.
// ---------------------------------------------------------------------------
template<int N, int K>
__global__ __launch_bounds__(256, 2)
void gemm_xw_mfma(const float* __restrict__ X, const ushort_t* __restrict__ Wab,
                  const float* __restrict__ ba, const float* __restrict__ bb,
                  ushort_t* __restrict__ OutA, ushort_t* __restrict__ OutB, int M)
{
    constexpr int KC = K / 32;                  // MFMA K-chains
    constexpr int NT = N / 16;                  // 16-col tiles
    __shared__ ushort_t sW[N * K];
    __shared__ ushort_t sX[64 * K];
    const int tid = threadIdx.x;
    const int m0  = blockIdx.x * 64;

    auto swz = [](int r, int e) {               // elem e within row r -> phys
        return r * K + ((((e >> 3) ^ (r & 7)) << 3) | (e & 7));
    };

    // stage W: plain 16B copies of pre-converted bf16
    constexpr int WQ8 = N * K / 8;
    for (int q = tid; q < WQ8; q += 256) {
        int nrow = q / (K / 8);
        int e8   = (q % (K / 8)) * 8;
        uint4 v = *(const uint4*)(Wab + (size_t)nrow * K + e8);
        *(uint4*)&sW[swz(nrow, e8)] = v;
    }
    // stage X tile -> bf16 LDS (zero-pad past M)
    constexpr int XQ = 64 * (K / 4);
    for (int q = tid; q < XQ; q += 256) {
        int r  = q / (K / 4);
        int k4 = (q % (K / 4)) * 4;
        float4 v = make_float4(0.f, 0.f, 0.f, 0.f);
        int gr = m0 + r;
        if (gr < M) v = *(const float4*)(X + (size_t)gr * K + k4);
        short4 h = make_short4((short)f2bf(v.x), (short)f2bf(v.y),
                               (short)f2bf(v.z), (short)f2bf(v.w));
        *(short4*)&sX[swz(r, k4)] = h;
    }
    __syncthreads();

    const int wv   = tid >> 6;                  // wave -> rows wv*16..+15
    const int lane = tid & 63;
    const int mrow = lane & 15;
    const int quad = lane >> 4;

    bf16x8 a[KC];
    #pragma unroll
    for (int kc = 0; kc < KC; ++kc)
        a[kc] = *(const bf16x8*)&sX[swz(wv * 16 + mrow, kc * 32 + quad * 8)];

    #pragma unroll
    for (int nt = 0; nt < NT; ++nt) {
        f32x4 acc = {0.f, 0.f, 0.f, 0.f};
        #pragma unroll
        for (int kc = 0; kc < KC; ++kc) {
            bf16x8 bfr = *(const bf16x8*)&sW[swz(nt * 16 + mrow, kc * 32 + quad * 8)];
            acc = __builtin_amdgcn_mfma_f32_16x16x32_bf16(a[kc], bfr, acc, 0, 0, 0);
        }
        const int col = nt * 16 + mrow;
        ushort_t* dst;
        int cc;
        float bv;
        if (col < N / 2) { dst = OutA; cc = col;         bv = ba[cc]; }
        else             { dst = OutB; cc = col - N / 2; bv = bb[cc]; }
        #pragma unroll
        for (int r = 0; r < 4; ++r) {
            int row = m0 + wv * 16 + quad * 4 + r;
            if (row < M)
                dst[(size_t)row * (N / 2) + cc] = f2bf(acc[r] + bv);
        }
    }
}

// ---------------------------------------------------------------------------
// Per-node GATv2 attention + aggregation — r13-proven version.
// bf16 xl/xr, LPE=D/4 lanes/edge, 4-deep prefetch, tail + self-loop gathers
// hoisted into the entry prefetch. ACT: 0 = ELU, 1 = softplus + 1e-4.
// ---------------------------------------------------------------------------
template<int D, int ACT>
__global__ __launch_bounds__(256)
void edge_attn(const ushort_t* __restrict__ xl, const ushort_t* __restrict__ xr,
               const float* __restrict__ We, const float* __restrict__ att,
               const float* __restrict__ bias,
               const int* __restrict__ row_off, const int2* __restrict__ slot,
               float* __restrict__ out, int n)
{
    constexpr int LPE = D / 4;                 // lanes per edge
    constexpr int SG  = 64 / LPE;              // edges per round
    const int lane = threadIdx.x & 63;
    const int wid  = threadIdx.x >> 6;
    const int t    = lane % LPE;               // owns dims 4t..4t+3
    const int g    = lane / LPE;               // edge slot within round
    const int node = blockIdx.x * 4 + wid;
    if (node >= n) return;

    auto unpack = [](uint2 d) -> float4 {
        float4 r;
        r.x = __uint_as_float(d.x << 16);
        r.y = __uint_as_float(d.x & 0xffff0000u);
        r.z = __uint_as_float(d.y << 16);
        r.w = __uint_as_float(d.y & 0xffff0000u);
        return r;
    };

    const float4 We4   = *(const float4*)(We   + 4 * t);
    const float4 att4  = *(const float4*)(att  + 4 * t);
    const float4 bias4 = *(const float4*)(bias + 4 * t);
    const float4 xr4   = unpack(*(const uint2*)(xr + (size_t)node * D + 4 * t));

    const int start = row_off[node];
    const int end   = row_off[node + 1];
    const int R  = (end - start) / SG;         // full rounds
    const int jt = start + R * SG;             // tail begin
    const bool has_tail = jt < end;

    // ---- entry prefetch: main pipeline + tail + self-loop all in flight ----
    int2  q[4];
    uint2 xv[4];
    #pragma unroll
    for (int s = 0; s < 4; ++s) {
        if (s < R) {
            q[s]  = slot[start + s * SG + g];
            xv[s] = *(const uint2*)(xl + (size_t)q[s].x * D + 4 * t);
        }
    }
    int2 tq = make_int2(0, 0);
    uint2 tx = make_uint2(0u, 0u);
    if (has_tail) {
        int idx = min(jt + g, end - 1);
        tq = slot[idx];
        tx = *(const uint2*)(xl + (size_t)tq.x * D + 4 * t);
    }
    const uint2 xs = *(const uint2*)(xl + (size_t)node * D + 4 * t); // self

    float denom = 0.f, wsum = 0.f;
    float4 acc = make_float4(0.f, 0.f, 0.f, 0.f);

    auto body = [&](int2 qe, float4 xvv, bool active) {
        float w = __int_as_float(qe.y);
        float4 v;
        v.x = xvv.x + fmaf(w, We4.x, xr4.x);
        v.y = xvv.y + fmaf(w, We4.y, xr4.y);
        v.z = xvv.z + fmaf(w, We4.z, xr4.z);
        v.w = xvv.w + fmaf(w, We4.w, xr4.w);
        float4 m;
        m.x = fmaxf(v.x, 0.2f * v.x);
        m.y = fmaxf(v.y, 0.2f * v.y);
        m.z = fmaxf(v.z, 0.2f * v.z);
        m.w = fmaxf(v.w, 0.2f * v.w);
        float p = att4.x * m.x + att4.y * m.y + att4.z * m.z + att4.w * m.w;
        p = group_reduce<LPE>(p);              // per-edge score, DPP only
        float e = active ? __expf(p) : 0.f;
        wsum  += active ? w : 0.f;
        denom += e;
        acc.x = fmaf(e, xvv.x, acc.x);
        acc.y = fmaf(e, xvv.y, acc.y);
        acc.z = fmaf(e, xvv.z, acc.z);
        acc.w = fmaf(e, xvv.w, acc.w);
    };

    int b = 0;
    for (; b + 4 <= R; b += 4) {               // steady state
        #pragma unroll
        for (int s = 0; s < 4; ++s) {
            int2 cq = q[s]; uint2 cx = xv[s];
            int nr = b + 4 + s;
            if (nr < R) {                      // refill stage s
                q[s]  = slot[start + nr * SG + g];
                xv[s] = *(const uint2*)(xl + (size_t)q[s].x * D + 4 * t);
            }
            body(cq, unpack(cx), true);
        }
    }
    #pragma unroll
    for (int s = 0; s < 4; ++s)                // leftover full rounds
        if (b + s < R) body(q[s], unpack(xv[s]), true);

    if (has_tail)                              // tail round (data prefetched)
        body(tq, unpack(tx), (jt + g) < end);

    // combine partials across the SG subgroups (once per node)
    #pragma unroll
    for (int mask = LPE; mask < 64; mask <<= 1) {
        denom += __shfl_xor(denom, mask);
        wsum  += __shfl_xor(wsum,  mask);
        acc.x += __shfl_xor(acc.x, mask);
        acc.y += __shfl_xor(acc.y, mask);
        acc.z += __shfl_xor(acc.z, mask);
        acc.w += __shfl_xor(acc.w, mask);
    }

    {   // self-loop: w = mean of incoming edge weights (xs prefetched)
        float w = wsum / (float)max(end - start, 1);
        float4 xvs = unpack(xs);
        float4 v;
        v.x = xvs.x + fmaf(w, We4.x, xr4.x);
        v.y = xvs.y + fmaf(w, We4.y, xr4.y);
        v.z = xvs.z + fmaf(w, We4.z, xr4.z);
        v.w = xvs.w + fmaf(w, We4.w, xr4.w);
        float4 m;
        m.x = fmaxf(v.x, 0.2f * v.x);
        m.y = fmaxf(v.y, 0.2f * v.y);
        m.z = fmaxf(v.z, 0.2f * v.z);
        m.w = fmaxf(v.w, 0.2f * v.w);
        float p = att4.x * m.x + att4.y * m.y + att4.z * m.z + att4.w * m.w;
        p = group_reduce<LPE>(p);
        float e = __expf(p);
        denom += e;
        acc.x = fmaf(e, xvs.x, acc.x);
        acc.y = fmaf(e, xvs.y, acc.y);
        acc.z = fmaf(e, xvs.z, acc.z);
        acc.w = fmaf(e, xvs.w, acc.w);
    }

    float4 res;
    res.x = acc.x / denom + bias4.x;
    res.y = acc.y / denom + bias4.y;
    res.z = acc.z / denom + bias4.z;
    res.w = acc.w / denom + bias4.w;
    if (ACT == 0) {
        // ELU via hw exp: max(r,0) + exp(min(r,0)) - 1   (exact for r>=0)
        res.x = fmaxf(res.x, 0.f) + __expf(fminf(res.x, 0.f)) - 1.f;
        res.y = fmaxf(res.y, 0.f) + __expf(fminf(res.y, 0.f)) - 1.f;
        res.z = fmaxf(res.z, 0.f) + __expf(fminf(res.z, 0.f)) - 1.f;
        res.w = fmaxf(res.w, 0.f) + __expf(fminf(res.w, 0.f)) - 1.f;
    } else {
        // softplus via hw exp/log + 1e-4
        res.x = fmaxf(res.x, 0.f) + __logf(1.f + __expf(-fabsf(res.x))) + 1e-4f;
        res.y = fmaxf(res.y, 0.f) + __logf(1.f + __expf(-fabsf(res.y))) + 1e-4f;
        res.z = fmaxf(res.z, 0.f) + __logf(1.f + __expf(-fabsf(res.z))) + 1e-4f;
        res.w = fmaxf(res.w, 0.f) + __logf(1.f + __expf(-fabsf(res.w))) + 1e-4f;
    }
    if (g == 0)
        *(float4*)(out + (size_t)node * D + 4 * t) = res;
}

// ---------------------------------------------------------------------------
extern "C" void kernel_launch(void* const* d_in, const int* in_sizes, int n_in,
                              void* d_out, int out_size, void* d_ws, size_t ws_size,
                              hipStream_t stream)
{
    const float* x     = (const float*)d_in[0];
    const int*   ei    = (const int*)d_in[1];     // (2, E) int32
    const float* ew    = (const float*)d_in[2];
    const float* Wl1   = (const float*)d_in[3];
    const float* bl1   = (const float*)d_in[4];
    const float* Wr1   = (const float*)d_in[5];
    const float* br1   = (const float*)d_in[6];
    const float* We1   = (const float*)d_in[7];
    const float* att1  = (const float*)d_in[8];
    const float* bias1 = (const float*)d_in[9];
    const float* Wl2   = (const float*)d_in[10];
    const float* bl2   = (const float*)d_in[11];
    const float* Wr2   = (const float*)d_in[12];
    const float* br2   = (const float*)d_in[13];
    const float* We2   = (const float*)d_in[14];
    const float* att2  = (const float*)d_in[15];
    const float* bias2 = (const float*)d_in[16];
    float* out = (float*)d_out;

    const int n = in_sizes[0] / 128;
    const int E = in_sizes[2];
    const int NB = (n + 255) / 256;               // 196 (<= 256 required)

    char* wp = (char*)d_ws;
    auto carve = [&](size_t bytes) -> void* {
        void* p = (void*)wp;
        wp += (bytes + 255) & ~(size_t)255;
        return p;
    };
    int*      cnt     = (int*)     carve((size_t)n * 4);
    int*      row_off = (int*)     carve((size_t)(n + 1) * 4);
    int*      rank    = (int*)     carve((size_t)E * 4);
    int2*     slot    = (int2*)    carve((size_t)E * 8);
    ushort_t* wab1    = (ushort_t*)carve((size_t)2 * 64 * 128 * 2);
    ushort_t* wab2    = (ushort_t*)carve((size_t)2 * 32 * 64 * 2);
    ushort_t* xl1     = (ushort_t*)carve((size_t)n * 64 * 2);
    ushort_t* xr1     = (ushort_t*)carve((size_t)n * 64 * 2);
    float*    hbuf    = (float*)   carve((size_t)n * 64 * 4);
    ushort_t* xl2     = (ushort_t*)carve((size_t)n * 32 * 2);
    ushort_t* xr2     = (ushort_t*)carve((size_t)n * 32 * 2);

    setup_kernel  <<<256, 256, 0, stream>>>(Wl1, Wr1, Wl2, Wr2, wab1, wab2, cnt, n);
    deg_kernel    <<<(E + 255) / 256, 256, 0, stream>>>(ei, cnt, rank, E);
    scan_all      <<<NB, 256, 0, stream>>>(cnt, row_off, n, NB);
    scatter_kernel<<<(E + 255) / 256, 256, 0, stream>>>(ei, ew, row_off, rank, slot, E);

    // layer 1
    gemm_xw_mfma<128, 128><<<(n + 63) / 64, 256, 0, stream>>>(x, wab1, bl1, br1,
                                                              xl1, xr1, n);
    edge_attn<64, 0><<<(n + 3) / 4, 256, 0, stream>>>(xl1, xr1, We1, att1, bias1,
                                                      row_off, slot, hbuf, n);
    // layer 2
    gemm_xw_mfma<64, 64><<<(n + 63) / 64, 256, 0, stream>>>(hbuf, wab2, bl2, br2,
                                                            xl2, xr2, n);
    edge_attn<32, 1><<<(n + 3) / 4, 256, 0, stream>>>(xl2, xr2, We2, att2, bias2,
                                                      row_off, slot, out, n);
}

// Round 15
// 251.932 us; speedup vs baseline: 1.0360x; 1.0360x over previous
//
#include <hip/hip_runtime.h>
#include <math.h>

typedef unsigned short ushort_t;
typedef __attribute__((ext_vector_type(8))) short bf16x8;   // MFMA A/B frag (4 VGPR)
typedef __attribute__((ext_vector_type(4))) float f32x4;    // MFMA C/D frag

// ---------------------------------------------------------------------------
// DPP-based add: x += x[lane ^ pattern], pure VALU.
// ---------------------------------------------------------------------------
template<int CTRL>
__device__ __forceinline__ float dpp_addf(float x)
{
    int y = __builtin_amdgcn_update_dpp(0, __float_as_int(x), CTRL, 0xf, 0xf, true);
    return x + __int_as_float(y);
}

template<int LPE>
__device__ __forceinline__ float group_reduce(float p)
{
    p = dpp_addf<0xB1>(p);                           // xor 1
    p = dpp_addf<0x4E>(p);                           // xor 2
    if constexpr (LPE >= 8)  p = dpp_addf<0x141>(p); // xor 7
    if constexpr (LPE >= 16) p = dpp_addf<0x140>(p); // xor 15
    return p;
}

__device__ __forceinline__ ushort_t f2bf(float f)
{
    unsigned u = __float_as_uint(f);
    return (ushort_t)((u + 0x7fffu + ((u >> 16) & 1u)) >> 16);   // RNE
}

// ---------------------------------------------------------------------------
// setup: zero cnt + convert all four weight matrices to bf16 (r14-kept).
// ---------------------------------------------------------------------------
__global__ __launch_bounds__(256)
void setup_kernel(const float* __restrict__ Wl1, const float* __restrict__ Wr1,
                  const float* __restrict__ Wl2, const float* __restrict__ Wr2,
                  ushort_t* __restrict__ wab1, ushort_t* __restrict__ wab2,
                  int* __restrict__ cnt, int n)
{
    const int T = gridDim.x * 256;
    const int i0 = blockIdx.x * 256 + threadIdx.x;
    for (int k = i0; k < n; k += T) cnt[k] = 0;
    for (int k = i0; k < 2 * 64 * 128; k += T)
        wab1[k] = f2bf(k < 64 * 128 ? Wl1[k] : Wr1[k - 64 * 128]);
    for (int k = i0; k < 2 * 32 * 64; k += T)
        wab2[k] = f2bf(k < 32 * 64 ? Wl2[k] : Wr2[k - 32 * 64]);
}

// ---------------------------------------------------------------------------
// Fused [deg | gemm1] dispatch: blocks < degBlocks run the in-degree count
// (+ per-edge rank), the rest run the layer-1 MFMA GEMM. The two are data-
// independent; deg is atomic-LATENCY-bound, gemm is MFMA-bound -> they
// overlap on the device instead of serializing (r14 post-mortem: deg+scatter
// are the hidden heavies, launch gaps are small).
// GEMM layouts HW-verified (m89/m91): A/B frag [m|n=lane&15][k=quad*8+j];
// C/D col=lane&15, row=quad*4+reg. XOR-granule swizzle kills bank conflicts.
// ---------------------------------------------------------------------------
template<int N, int K>
__global__ __launch_bounds__(256, 2)
void deg_plus_gemm(const int* __restrict__ ei, int* __restrict__ cnt,
                   int* __restrict__ rank, int E, int degBlocks,
                   const float* __restrict__ X, const ushort_t* __restrict__ Wab,
                   const float* __restrict__ ba, const float* __restrict__ bb,
                   ushort_t* __restrict__ OutA, ushort_t* __restrict__ OutB, int M)
{
    constexpr int KC = K / 32;
    constexpr int NT = N / 16;
    __shared__ ushort_t sW[N * K];
    __shared__ ushort_t sX[64 * K];
    const int tid = threadIdx.x;

    if (blockIdx.x < degBlocks) {               // ---- deg path ----
        int e = blockIdx.x * 256 + tid;
        if (e < E) rank[e] = atomicAdd(&cnt[ei[E + e]], 1);
        return;
    }

    // ---- gemm path ----
    const int m0 = (blockIdx.x - degBlocks) * 64;

    auto swz = [](int r, int e) {
        return r * K + ((((e >> 3) ^ (r & 7)) << 3) | (e & 7));
    };

    constexpr int WQ8 = N * K / 8;
    for (int q = tid; q < WQ8; q += 256) {
        int nrow = q / (K / 8);
        int e8   = (q % (K / 8)) * 8;
        uint4 v = *(const uint4*)(Wab + (size_t)nrow * K + e8);
        *(uint4*)&sW[swz(nrow, e8)] = v;
    }
    constexpr int XQ = 64 * (K / 4);
    for (int q = tid; q < XQ; q += 256) {
        int r  = q / (K / 4);
        int k4 = (q % (K / 4)) * 4;
        float4 v = make_float4(0.f, 0.f, 0.f, 0.f);
        int gr = m0 + r;
        if (gr < M) v = *(const float4*)(X + (size_t)gr * K + k4);
        short4 h = make_short4((short)f2bf(v.x), (short)f2bf(v.y),
                               (short)f2bf(v.z), (short)f2bf(v.w));
        *(short4*)&sX[swz(r, k4)] = h;
    }
    __syncthreads();

    const int wv   = tid >> 6;
    const int lane = tid & 63;
    const int mrow = lane & 15;
    const int quad = lane >> 4;

    bf16x8 a[KC];
    #pragma unroll
    for (int kc = 0; kc < KC; ++kc)
        a[kc] = *(const bf16x8*)&sX[swz(wv * 16 + mrow, kc * 32 + quad * 8)];

    #pragma unroll
    for (int nt = 0; nt < NT; ++nt) {
        f32x4 acc = {0.f, 0.f, 0.f, 0.f};
        #pragma unroll
        for (int kc = 0; kc < KC; ++kc) {
            bf16x8 bfr = *(const bf16x8*)&sW[swz(nt * 16 + mrow, kc * 32 + quad * 8)];
            acc = __builtin_amdgcn_mfma_f32_16x16x32_bf16(a[kc], bfr, acc, 0, 0, 0);
        }
        const int col = nt * 16 + mrow;
        ushort_t* dst;
        int cc;
        float bv;
        if (col < N / 2) { dst = OutA; cc = col;         bv = ba[cc]; }
        else             { dst = OutB; cc = col - N / 2; bv = bb[cc]; }
        #pragma unroll
        for (int r = 0; r < 4; ++r) {
            int row = m0 + wv * 16 + quad * 4 + r;
            if (row < M)
                dst[(size_t)row * (N / 2) + cc] = f2bf(acc[r] + bv);
        }
    }
}

// ---------------------------------------------------------------------------
// scan pair (r13-proven; r14's single-dispatch scan_all cost ~10us of
// redundant L2 reads and was reverted)
// ---------------------------------------------------------------------------
__global__ __launch_bounds__(256)
void scan_p1(const int* __restrict__ cnt, int* __restrict__ bsums, int n)
{
    __shared__ int s[256];
    const int tid = threadIdx.x;
    int gi = blockIdx.x * 256 + tid;
    s[tid] = (gi < n) ? cnt[gi] : 0;
    __syncthreads();
    #pragma unroll
    for (int off = 128; off >= 1; off >>= 1) {
        if (tid < off) s[tid] += s[tid + off];
        __syncthreads();
    }
    if (tid == 0) bsums[blockIdx.x] = s[0];
}

__global__ __launch_bounds__(256)
void scan_p3(const int* __restrict__ cnt, const int* __restrict__ bsums,
             int* __restrict__ row_off, int n, int nb)
{
    __shared__ int sb[256];
    __shared__ int s[256];
    const int tid = threadIdx.x;

    int bv = (tid < nb) ? bsums[tid] : 0;
    sb[tid] = bv;
    __syncthreads();
    #pragma unroll
    for (int off = 1; off < 256; off <<= 1) {       // inclusive scan of bsums
        int t = (tid >= off) ? sb[tid - off] : 0;
        __syncthreads();
        sb[tid] += t;
        __syncthreads();
    }
    int excl_t = sb[tid] - bv;                      // exclusive
    __syncthreads();
    sb[tid] = excl_t;
    __syncthreads();
    const int base = sb[blockIdx.x];

    int gi = blockIdx.x * 256 + tid;
    int c = (gi < n) ? cnt[gi] : 0;
    s[tid] = c;
    __syncthreads();
    #pragma unroll
    for (int off = 1; off < 256; off <<= 1) {       // inclusive scan of tile
        int t = (tid >= off) ? s[tid - off] : 0;
        __syncthreads();
        s[tid] += t;
        __syncthreads();
    }
    if (gi < n) {
        int excl = base + s[tid] - c;
        row_off[gi] = excl;
        if (gi == n - 1) row_off[n] = excl + c;     // == E
    }
}

// atomic-free scatter: slot position = row_off[dst] + rank
__global__ __launch_bounds__(256)
void scatter_kernel(const int* __restrict__ ei, const float* __restrict__ ew,
                    const int* __restrict__ row_off, const int* __restrict__ rank,
                    int2* __restrict__ slot, int E)
{
    int e = blockIdx.x * 256 + threadIdx.x;
    if (e >= E) return;
    int d = ei[E + e];
    slot[row_off[d] + rank[e]] = make_int2(ei[e], __float_as_int(ew[e]));
}

// ---------------------------------------------------------------------------
// MFMA fused linear (standalone, used for layer 2) — r13-proven.
// ---------------------------------------------------------------------------
template<int N, int K>
__global__ __launch_bounds__(256, 2)
void gemm_xw_mfma(const float* __restrict__ X, const ushort_t* __restrict__ Wab,
                  const float* __restrict__ ba, const float* __restrict__ bb,
                  ushort_t* __restrict__ OutA, ushort_t* __restrict__ OutB, int M)
{
    constexpr int KC = K / 32;
    constexpr int NT = N / 16;
    __shared__ ushort_t sW[N * K];
    __shared__ ushort_t sX[64 * K];
    const int tid = threadIdx.x;
    const int m0  = blockIdx.x * 64;

    auto swz = [](int r, int e) {
        return r * K + ((((e >> 3) ^ (r & 7)) << 3) | (e & 7));
    };

    constexpr int WQ8 = N * K / 8;
    for (int q = tid; q < WQ8; q += 256) {
        int nrow = q / (K / 8);
        int e8   = (q % (K / 8)) * 8;
        uint4 v = *(const uint4*)(Wab + (size_t)nrow * K + e8);
        *(uint4*)&sW[swz(nrow, e8)] = v;
    }
    constexpr int XQ = 64 * (K / 4);
    for (int q = tid; q < XQ; q += 256) {
        int r  = q / (K / 4);
        int k4 = (q % (K / 4)) * 4;
        float4 v = make_float4(0.f, 0.f, 0.f, 0.f);
        int gr = m0 + r;
        if (gr < M) v = *(const float4*)(X + (size_t)gr * K + k4);
        short4 h = make_short4((short)f2bf(v.x), (short)f2bf(v.y),
                               (short)f2bf(v.z), (short)f2bf(v.w));
        *(short4*)&sX[swz(r, k4)] = h;
    }
    __syncthreads();

    const int wv   = tid >> 6;
    const int lane = tid & 63;
    const int mrow = lane & 15;
    const int quad = lane >> 4;

    bf16x8 a[KC];
    #pragma unroll
    for (int kc = 0; kc < KC; ++kc)
        a[kc] = *(const bf16x8*)&sX[swz(wv * 16 + mrow, kc * 32 + quad * 8)];

    #pragma unroll
    for (int nt = 0; nt < NT; ++nt) {
        f32x4 acc = {0.f, 0.f, 0.f, 0.f};
        #pragma unroll
        for (int kc = 0; kc < KC; ++kc) {
            bf16x8 bfr = *(const bf16x8*)&sW[swz(nt * 16 + mrow, kc * 32 + quad * 8)];
            acc = __builtin_amdgcn_mfma_f32_16x16x32_bf16(a[kc], bfr, acc, 0, 0, 0);
        }
        const int col = nt * 16 + mrow;
        ushort_t* dst;
        int cc;
        float bv;
        if (col < N / 2) { dst = OutA; cc = col;         bv = ba[cc]; }
        else             { dst = OutB; cc = col - N / 2; bv = bb[cc]; }
        #pragma unroll
        for (int r = 0; r < 4; ++r) {
            int row = m0 + wv * 16 + quad * 4 + r;
            if (row < M)
                dst[(size_t)row * (N / 2) + cc] = f2bf(acc[r] + bv);
        }
    }
}

// ---------------------------------------------------------------------------
// Per-node GATv2 attention + aggregation — r13-proven version.
// bf16 xl/xr, LPE=D/4 lanes/edge, 4-deep prefetch, tail + self-loop gathers
// hoisted into the entry prefetch. ACT: 0 = ELU, 1 = softplus + 1e-4.
// ---------------------------------------------------------------------------
template<int D, int ACT>
__global__ __launch_bounds__(256)
void edge_attn(const ushort_t* __restrict__ xl, const ushort_t* __restrict__ xr,
               const float* __restrict__ We, const float* __restrict__ att,
               const float* __restrict__ bias,
               const int* __restrict__ row_off, const int2* __restrict__ slot,
               float* __restrict__ out, int n)
{
    constexpr int LPE = D / 4;                 // lanes per edge
    constexpr int SG  = 64 / LPE;              // edges per round
    const int lane = threadIdx.x & 63;
    const int wid  = threadIdx.x >> 6;
    const int t    = lane % LPE;               // owns dims 4t..4t+3
    const int g    = lane / LPE;               // edge slot within round
    const int node = blockIdx.x * 4 + wid;
    if (node >= n) return;

    auto unpack = [](uint2 d) -> float4 {
        float4 r;
        r.x = __uint_as_float(d.x << 16);
        r.y = __uint_as_float(d.x & 0xffff0000u);
        r.z = __uint_as_float(d.y << 16);
        r.w = __uint_as_float(d.y & 0xffff0000u);
        return r;
    };

    const float4 We4   = *(const float4*)(We   + 4 * t);
    const float4 att4  = *(const float4*)(att  + 4 * t);
    const float4 bias4 = *(const float4*)(bias + 4 * t);
    const float4 xr4   = unpack(*(const uint2*)(xr + (size_t)node * D + 4 * t));

    const int start = row_off[node];
    const int end   = row_off[node + 1];
    const int R  = (end - start) / SG;         // full rounds
    const int jt = start + R * SG;             // tail begin
    const bool has_tail = jt < end;

    // ---- entry prefetch: main pipeline + tail + self-loop all in flight ----
    int2  q[4];
    uint2 xv[4];
    #pragma unroll
    for (int s = 0; s < 4; ++s) {
        if (s < R) {
            q[s]  = slot[start + s * SG + g];
            xv[s] = *(const uint2*)(xl + (size_t)q[s].x * D + 4 * t);
        }
    }
    int2 tq = make_int2(0, 0);
    uint2 tx = make_uint2(0u, 0u);
    if (has_tail) {
        int idx = min(jt + g, end - 1);
        tq = slot[idx];
        tx = *(const uint2*)(xl + (size_t)tq.x * D + 4 * t);
    }
    const uint2 xs = *(const uint2*)(xl + (size_t)node * D + 4 * t); // self

    float denom = 0.f, wsum = 0.f;
    float4 acc = make_float4(0.f, 0.f, 0.f, 0.f);

    auto body = [&](int2 qe, float4 xvv, bool active) {
        float w = __int_as_float(qe.y);
        float4 v;
        v.x = xvv.x + fmaf(w, We4.x, xr4.x);
        v.y = xvv.y + fmaf(w, We4.y, xr4.y);
        v.z = xvv.z + fmaf(w, We4.z, xr4.z);
        v.w = xvv.w + fmaf(w, We4.w, xr4.w);
        float4 m;
        m.x = fmaxf(v.x, 0.2f * v.x);
        m.y = fmaxf(v.y, 0.2f * v.y);
        m.z = fmaxf(v.z, 0.2f * v.z);
        m.w = fmaxf(v.w, 0.2f * v.w);
        float p = att4.x * m.x + att4.y * m.y + att4.z * m.z + att4.w * m.w;
        p = group_reduce<LPE>(p);              // per-edge score, DPP only
        float e = active ? __expf(p) : 0.f;
        wsum  += active ? w : 0.f;
        denom += e;
        acc.x = fmaf(e, xvv.x, acc.x);
        acc.y = fmaf(e, xvv.y, acc.y);
        acc.z = fmaf(e, xvv.z, acc.z);
        acc.w = fmaf(e, xvv.w, acc.w);
    };

    int b = 0;
    for (; b + 4 <= R; b += 4) {               // steady state
        #pragma unroll
        for (int s = 0; s < 4; ++s) {
            int2 cq = q[s]; uint2 cx = xv[s];
            int nr = b + 4 + s;
            if (nr < R) {                      // refill stage s
                q[s]  = slot[start + nr * SG + g];
                xv[s] = *(const uint2*)(xl + (size_t)q[s].x * D + 4 * t);
            }
            body(cq, unpack(cx), true);
        }
    }
    #pragma unroll
    for (int s = 0; s < 4; ++s)                // leftover full rounds
        if (b + s < R) body(q[s], unpack(xv[s]), true);

    if (has_tail)                              // tail round (data prefetched)
        body(tq, unpack(tx), (jt + g) < end);

    // combine partials across the SG subgroups (once per node)
    #pragma unroll
    for (int mask = LPE; mask < 64; mask <<= 1) {
        denom += __shfl_xor(denom, mask);
        wsum  += __shfl_xor(wsum,  mask);
        acc.x += __shfl_xor(acc.x, mask);
        acc.y += __shfl_xor(acc.y, mask);
        acc.z += __shfl_xor(acc.z, mask);
        acc.w += __shfl_xor(acc.w, mask);
    }

    {   // self-loop: w = mean of incoming edge weights (xs prefetched)
        float w = wsum / (float)max(end - start, 1);
        float4 xvs = unpack(xs);
        float4 v;
        v.x = xvs.x + fmaf(w, We4.x, xr4.x);
        v.y = xvs.y + fmaf(w, We4.y, xr4.y);
        v.z = xvs.z + fmaf(w, We4.z, xr4.z);
        v.w = xvs.w + fmaf(w, We4.w, xr4.w);
        float4 m;
        m.x = fmaxf(v.x, 0.2f * v.x);
        m.y = fmaxf(v.y, 0.2f * v.y);
        m.z = fmaxf(v.z, 0.2f * v.z);
        m.w = fmaxf(v.w, 0.2f * v.w);
        float p = att4.x * m.x + att4.y * m.y + att4.z * m.z + att4.w * m.w;
        p = group_reduce<LPE>(p);
        float e = __expf(p);
        denom += e;
        acc.x = fmaf(e, xvs.x, acc.x);
        acc.y = fmaf(e, xvs.y, acc.y);
        acc.z = fmaf(e, xvs.z, acc.z);
        acc.w = fmaf(e, xvs.w, acc.w);
    }

    float4 res;
    res.x = acc.x / denom + bias4.x;
    res.y = acc.y / denom + bias4.y;
    res.z = acc.z / denom + bias4.z;
    res.w = acc.w / denom + bias4.w;
    if (ACT == 0) {
        // ELU via hw exp: max(r,0) + exp(min(r,0)) - 1   (exact for r>=0)
        res.x = fmaxf(res.x, 0.f) + __expf(fminf(res.x, 0.f)) - 1.f;
        res.y = fmaxf(res.y, 0.f) + __expf(fminf(res.y, 0.f)) - 1.f;
        res.z = fmaxf(res.z, 0.f) + __expf(fminf(res.z, 0.f)) - 1.f;
        res.w = fmaxf(res.w, 0.f) + __expf(fminf(res.w, 0.f)) - 1.f;
    } else {
        // softplus via hw exp/log + 1e-4
        res.x = fmaxf(res.x, 0.f) + __logf(1.f + __expf(-fabsf(res.x))) + 1e-4f;
        res.y = fmaxf(res.y, 0.f) + __logf(1.f + __expf(-fabsf(res.y))) + 1e-4f;
        res.z = fmaxf(res.z, 0.f) + __logf(1.f + __expf(-fabsf(res.z))) + 1e-4f;
        res.w = fmaxf(res.w, 0.f) + __logf(1.f + __expf(-fabsf(res.w))) + 1e-4f;
    }
    if (g == 0)
        *(float4*)(out + (size_t)node * D + 4 * t) = res;
}

// ---------------------------------------------------------------------------
extern "C" void kernel_launch(void* const* d_in, const int* in_sizes, int n_in,
                              void* d_out, int out_size, void* d_ws, size_t ws_size,
                              hipStream_t stream)
{
    const float* x     = (const float*)d_in[0];
    const int*   ei    = (const int*)d_in[1];     // (2, E) int32
    const float* ew    = (const float*)d_in[2];
    const float* Wl1   = (const float*)d_in[3];
    const float* bl1   = (const float*)d_in[4];
    const float* Wr1   = (const float*)d_in[5];
    const float* br1   = (const float*)d_in[6];
    const float* We1   = (const float*)d_in[7];
    const float* att1  = (const float*)d_in[8];
    const float* bias1 = (const float*)d_in[9];
    const float* Wl2   = (const float*)d_in[10];
    const float* bl2   = (const float*)d_in[11];
    const float* Wr2   = (const float*)d_in[12];
    const float* br2   = (const float*)d_in[13];
    const float* We2   = (const float*)d_in[14];
    const float* att2  = (const float*)d_in[15];
    const float* bias2 = (const float*)d_in[16];
    float* out = (float*)d_out;

    const int n = in_sizes[0] / 128;
    const int E = in_sizes[2];
    const int NB = (n + 255) / 256;               // 196 (<= 256 required)
    const int degBlocks  = (E + 255) / 256;
    const int gemmBlocks = (n + 63) / 64;

    char* wp = (char*)d_ws;
    auto carve = [&](size_t bytes) -> void* {
        void* p = (void*)wp;
        wp += (bytes + 255) & ~(size_t)255;
        return p;
    };
    int*      cnt     = (int*)     carve((size_t)n * 4);
    int*      row_off = (int*)     carve((size_t)(n + 1) * 4);
    int*      rank    = (int*)     carve((size_t)E * 4);
    int*      bsums   = (int*)     carve((size_t)256 * 4);
    int2*     slot    = (int2*)    carve((size_t)E * 8);
    ushort_t* wab1    = (ushort_t*)carve((size_t)2 * 64 * 128 * 2);
    ushort_t* wab2    = (ushort_t*)carve((size_t)2 * 32 * 64 * 2);
    ushort_t* xl1     = (ushort_t*)carve((size_t)n * 64 * 2);
    ushort_t* xr1     = (ushort_t*)carve((size_t)n * 64 * 2);
    float*    hbuf    = (float*)   carve((size_t)n * 64 * 4);
    ushort_t* xl2     = (ushort_t*)carve((size_t)n * 32 * 2);
    ushort_t* xr2     = (ushort_t*)carve((size_t)n * 32 * 2);

    setup_kernel<<<256, 256, 0, stream>>>(Wl1, Wr1, Wl2, Wr2, wab1, wab2, cnt, n);

    // fused: deg (atomic-latency-bound) || layer-1 GEMM (MFMA-bound)
    deg_plus_gemm<128, 128><<<degBlocks + gemmBlocks, 256, 0, stream>>>(
        ei, cnt, rank, E, degBlocks, x, wab1, bl1, br1, xl1, xr1, n);

    scan_p1       <<<NB, 256, 0, stream>>>(cnt, bsums, n);
    scan_p3       <<<NB, 256, 0, stream>>>(cnt, bsums, row_off, n, NB);
    scatter_kernel<<<(E + 255) / 256, 256, 0, stream>>>(ei, ew, row_off, rank, slot, E);

    edge_attn<64, 0><<<(n + 3) / 4, 256, 0, stream>>>(xl1, xr1, We1, att1, bias1,
                                                      row_off, slot, hbuf, n);
    gemm_xw_mfma<64, 64><<<(n + 63) / 64, 256, 0, stream>>>(hbuf, wab2, bl2, br2,
                                                            xl2, xr2, n);
    edge_attn<32, 1><<<(n + 3) / 4, 256, 0, stream>>>(xl2, xr2, We2, att2, bias2,
                                                      row_off, slot, out, n);
}